// Round 6
// baseline (186.757 us; speedup 1.0000x reference)
//
#include <hip/hip_runtime.h>
#include <math.h>

#define N_NODES 100000
#define DIM 64
#define N_EDGES 1600000

#define NBF 1563        // fine buckets: col >> 6 (ceil(100000/64) = 1563)
#define BK_NODES 64
#define CAP 1408        // per-bucket slab capacity (mean 1024, sigma ~32)

#define SC_CHUNK 8192
#define SC_BLOCKS ((N_EDGES + SC_CHUNK - 1) / SC_CHUNK)  // 196

#define GEMM_BLOCKS ((N_NODES / 16 + 15) / 16)  // 391 blocks x 16 waves
#define PH_BLOCKS (SC_BLOCKS + GEMM_BLOCKS)     // 587

typedef _Float16 half8 __attribute__((ext_vector_type(8)));
typedef _Float16 half4 __attribute__((ext_vector_type(4)));
typedef float f32x4 __attribute__((ext_vector_type(4)));

// ---------------------------------------------------------------------------
// Fused phase (block-specialized, 1024 threads) — byte-identical to round 1
// (best measured: < 41.7 us). Scan+stage scatter keeps pairs writes in long
// coalesced runs (direct-write variants cost +7 us from write-allocate).
// ---------------------------------------------------------------------------
__global__ __launch_bounds__(1024) void k_phase(
        const float* __restrict__ x,
        const float* __restrict__ Wm, const float* __restrict__ bm,
        const float* __restrict__ Wr, const float* __restrict__ br,
        const int* __restrict__ row, const int* __restrict__ col,
        int* __restrict__ cursor, unsigned int* __restrict__ pairs,
        _Float16* __restrict__ Mh, float* __restrict__ es,
        float* __restrict__ out) {
    __shared__ int cnt[NBF];     // histogram, then rebase (base_g - base_l)
    __shared__ int base_l[NBF];
    __shared__ int wsum[16];
    __shared__ int segtot;
    __shared__ unsigned int stage[SC_CHUNK];
    __shared__ unsigned short stage_bk[SC_CHUNK];

    const int t = threadIdx.x;
    const int lane = t & 63;
    const int wid = t >> 6;

    if (blockIdx.x < SC_BLOCKS) {
        const int start = blockIdx.x * SC_CHUNK;
        const int mEnd = min(N_EDGES, start + SC_CHUNK);

        for (int i = t; i < NBF; i += 1024) cnt[i] = 0;
        __syncthreads();

        int rr[8], cc[8], lr[8];
#pragma unroll
        for (int k = 0; k < 8; ++k) {
            const int idx = start + k * 1024 + t;
            if (idx < mEnd) {
                cc[k] = col[idx];
                rr[k] = row[idx];
                lr[k] = atomicAdd(&cnt[cc[k] >> 6], 1);
            }
        }
        __syncthreads();

        // segmented two-level exclusive scan over cnt[0..NBF): two 1024-wide
        // passes with carry (NBF = 1563 > blockDim).
        int segbase = 0;
        for (int s = 0; s < NBF; s += 1024) {
            const int i = s + t;
            const int v = (i < NBF) ? cnt[i] : 0;
            int inc = v;
#pragma unroll
            for (int o = 1; o < 64; o <<= 1) {
                const int u = __shfl_up(inc, o, 64);
                if (lane >= o) inc += u;
            }
            if (lane == 63) wsum[wid] = inc;
            __syncthreads();
            if (wid == 0) {
                const int wv = (lane < 16) ? wsum[lane] : 0;
                int winc = wv;
#pragma unroll
                for (int o = 1; o < 16; o <<= 1) {
                    const int u = __shfl_up(winc, o, 64);
                    if (lane >= o) winc += u;
                }
                if (lane < 16) wsum[lane] = winc - wv;  // exclusive wave offsets
            }
            __syncthreads();
            const int excl = segbase + inc - v + wsum[wid];
            if (i < NBF) {
                base_l[i] = excl;
                // rebase: gslot = base_g + (i - base_l) = cnt[i] + i later
                if (v > 0) cnt[i] = atomicAdd(&cursor[i], v) - excl;
            }
            if (t == 1023) segtot = excl + v;  // inclusive total of this segment
            __syncthreads();
            segbase = segtot;
        }

#pragma unroll
        for (int k = 0; k < 8; ++k) {
            const int idx = start + k * 1024 + t;
            if (idx < mEnd) {
                const int bk = cc[k] >> 6;
                const int slot = base_l[bk] + lr[k];
                stage[slot] = ((unsigned int)rr[k] << 6) | (unsigned int)(cc[k] & 63);
                stage_bk[slot] = (unsigned short)bk;
            }
        }
        __syncthreads();

        const int m = mEnd - start;
        for (int i = t; i < m; i += 1024) {
            const int bk = stage_bk[i];
            const int gslot = cnt[bk] + i;  // (base_g - base_l) + i
            if (gslot < CAP) pairs[(size_t)bk * CAP + gslot] = stage[i];
        }
        return;
    }

    // ---- GEMM branch ----
    const int wave = (blockIdx.x - SC_BLOCKS) * 16 + wid;
    if (wave >= N_NODES / 16) return;
    const int quad = lane >> 4;
    const int l15 = lane & 15;
    const int row0 = wave * 16;

    half8 bfrag[8][2];
#pragma unroll
    for (int ct = 0; ct < 8; ++ct) {
        const float* W = (ct < 4) ? Wm : Wr;
        const int c = (ct & 3) * 16 + l15;
#pragma unroll
        for (int kc = 0; kc < 2; ++kc) {
            half8 f;
#pragma unroll
            for (int j = 0; j < 8; ++j)
                f[j] = (_Float16)W[(kc * 32 + quad * 8 + j) * DIM + c];
            bfrag[ct][kc] = f;
        }
    }

    half8 afrag[2];
#pragma unroll
    for (int kc = 0; kc < 2; ++kc) {
        const float* xp = x + (size_t)(row0 + l15) * DIM + kc * 32 + quad * 8;
        const float4 x0 = *(const float4*)xp;
        const float4 x1 = *(const float4*)(xp + 4);
        half8 f;
        f[0] = (_Float16)x0.x; f[1] = (_Float16)x0.y;
        f[2] = (_Float16)x0.z; f[3] = (_Float16)x0.w;
        f[4] = (_Float16)x1.x; f[5] = (_Float16)x1.y;
        f[6] = (_Float16)x1.z; f[7] = (_Float16)x1.w;
        afrag[kc] = f;
    }

    f32x4 acc[8];
#pragma unroll
    for (int ct = 0; ct < 8; ++ct) {
        f32x4 a = {0.f, 0.f, 0.f, 0.f};
        a = __builtin_amdgcn_mfma_f32_16x16x32_f16(afrag[0], bfrag[ct][0], a, 0, 0, 0);
        a = __builtin_amdgcn_mfma_f32_16x16x32_f16(afrag[1], bfrag[ct][1], a, 0, 0, 0);
        acc[ct] = a;
    }

    float rsum[4] = {0.f, 0.f, 0.f, 0.f};
#pragma unroll
    for (int ct = 0; ct < 8; ++ct) {
        const float bias = (ct < 4) ? bm[(ct & 3) * 16 + l15]
                                    : br[(ct & 3) * 16 + l15];
#pragma unroll
        for (int r = 0; r < 4; ++r) {
            const float v = acc[ct][r] + bias;
            const size_t idx = (size_t)(row0 + quad * 4 + r) * DIM + (ct & 3) * 16 + l15;
            if (ct < 4) {
                Mh[idx] = (_Float16)v;
                rsum[r] += v;
            } else {
                out[idx] = v;
            }
        }
    }
#pragma unroll
    for (int o = 1; o <= 8; o <<= 1) {
#pragma unroll
        for (int r = 0; r < 4; ++r) rsum[r] += __shfl_xor(rsum[r], o, 64);
    }
    if (l15 == 0) {
#pragma unroll
        for (int r = 0; r < 4; ++r)
            es[row0 + quad * 4 + r] = __expf(rsum[r] * (1.0f / DIM));
    }
}

// ---------------------------------------------------------------------------
// Bucket gather: one 512-thread block per fine bucket (64 dst nodes).
// Round-1 structure; ONE change: 8-edge-deep inner unroll (was 4) so each
// 16-lane group keeps 8 Mh rows + 8 es loads in flight (latency-bound fix).
// ---------------------------------------------------------------------------
__global__ __launch_bounds__(512) void k_bucket_gather(
        const unsigned int* __restrict__ pairs, const int* __restrict__ cursor,
        const float* __restrict__ es, const half4* __restrict__ Mh4,
        float4* __restrict__ out4) {
    __shared__ unsigned int sorted[CAP];      // 5.5 KB
    __shared__ int cnt[BK_NODES];
    __shared__ int off[BK_NODES];
    const int b = blockIdx.x;
    const int t = threadIdx.x;
    const int lane = t & 63;
    const int wid = t >> 6;
    const int m = min(cursor[b], CAP);
    const size_t base = (size_t)b * CAP;

    if (t < BK_NODES) cnt[t] = 0;
    __syncthreads();

    unsigned int pk[3];
    int rk[3];
#pragma unroll
    for (int k = 0; k < 3; ++k) {
        const int i = k * 512 + t;
        if (i < m) {
            pk[k] = pairs[base + i];
            rk[k] = atomicAdd(&cnt[pk[k] & 63u], 1);
        }
    }
    __syncthreads();

    // exclusive scan over 64 counters: single wave shfl scan
    if (wid == 0) {
        const int v = cnt[lane];
        int inc = v;
#pragma unroll
        for (int o = 1; o < 64; o <<= 1) {
            const int u = __shfl_up(inc, o, 64);
            if (lane >= o) inc += u;
        }
        off[lane] = inc - v;
    }
    __syncthreads();

#pragma unroll
    for (int k = 0; k < 3; ++k) {
        const int i = k * 512 + t;
        if (i < m) sorted[off[pk[k] & 63u] + rk[k]] = pk[k];
    }
    __syncthreads();

    const int g = t >> 4;   // 32 groups of 16 lanes
    const int gl = t & 15;
    for (int c = g; c < BK_NODES; c += 32) {
        const int node = b * BK_NODES + c;
        if (node >= N_NODES) break;
        const int s0i = off[c];
        const int len = cnt[c];
        if (len == 0) continue;

        float ax[8][4];
        float lw[8];
#pragma unroll
        for (int q = 0; q < 8; ++q) {
            lw[q] = 0.f;
#pragma unroll
            for (int d = 0; d < 4; ++d) ax[q][d] = 0.f;
        }

        int j = 0;
        // 8-deep: issue all 16 loads (8 es + 8 Mh rows) before any FMA.
        for (; j + 7 < len; j += 8) {
            int s[8];
#pragma unroll
            for (int q = 0; q < 8; ++q) s[q] = (int)(sorted[s0i + j + q] >> 6);
            float w[8];
            half4 mm[8];
#pragma unroll
            for (int q = 0; q < 8; ++q) {
                w[q] = es[s[q]];
                mm[q] = Mh4[(size_t)s[q] * 16 + gl];
            }
#pragma unroll
            for (int q = 0; q < 8; ++q) {
                lw[q] += w[q];
                ax[q][0] = fmaf(w[q], (float)mm[q][0], ax[q][0]);
                ax[q][1] = fmaf(w[q], (float)mm[q][1], ax[q][1]);
                ax[q][2] = fmaf(w[q], (float)mm[q][2], ax[q][2]);
                ax[q][3] = fmaf(w[q], (float)mm[q][3], ax[q][3]);
            }
        }
        // 4-deep middle step
        for (; j + 3 < len; j += 4) {
            int s[4];
#pragma unroll
            for (int q = 0; q < 4; ++q) s[q] = (int)(sorted[s0i + j + q] >> 6);
#pragma unroll
            for (int q = 0; q < 4; ++q) {
                const float w = es[s[q]];
                const half4 mq = Mh4[(size_t)s[q] * 16 + gl];
                lw[q] += w;
                ax[q][0] = fmaf(w, (float)mq[0], ax[q][0]);
                ax[q][1] = fmaf(w, (float)mq[1], ax[q][1]);
                ax[q][2] = fmaf(w, (float)mq[2], ax[q][2]);
                ax[q][3] = fmaf(w, (float)mq[3], ax[q][3]);
            }
        }
        // scalar tail
        for (; j < len; ++j) {
            const int s0 = (int)(sorted[s0i + j] >> 6);
            const float w = es[s0];
            const half4 mq = Mh4[(size_t)s0 * 16 + gl];
            lw[0] += w;
            ax[0][0] = fmaf(w, (float)mq[0], ax[0][0]);
            ax[0][1] = fmaf(w, (float)mq[1], ax[0][1]);
            ax[0][2] = fmaf(w, (float)mq[2], ax[0][2]);
            ax[0][3] = fmaf(w, (float)mq[3], ax[0][3]);
        }

        float lsum = 0.f;
        float sx = 0.f, sy = 0.f, sz = 0.f, sw = 0.f;
#pragma unroll
        for (int q = 0; q < 8; ++q) {
            lsum += lw[q];
            sx += ax[q][0]; sy += ax[q][1]; sz += ax[q][2]; sw += ax[q][3];
        }
        const float inv = 1.0f / lsum;
        float4 r = out4[(size_t)node * 16 + gl];
        r.x = fmaf(sx, inv, r.x);
        r.y = fmaf(sy, inv, r.y);
        r.z = fmaf(sz, inv, r.z);
        r.w = fmaf(sw, inv, r.w);
        out4[(size_t)node * 16 + gl] = r;
    }
}

// ---------------------------------------------------------------------------
extern "C" void kernel_launch(void* const* d_in, const int* in_sizes, int n_in,
                              void* d_out, int out_size, void* d_ws, size_t ws_size,
                              hipStream_t stream) {
    const float* x  = (const float*)d_in[0];
    const int*   ei = (const int*)d_in[1];
    const float* Wm = (const float*)d_in[2];
    const float* bm = (const float*)d_in[3];
    const float* Wr = (const float*)d_in[4];
    const float* br = (const float*)d_in[5];
    float* out = (float*)d_out;
    const int* row = ei;            // edge_index[0]
    const int* col = ei + N_EDGES;  // edge_index[1]

    char* ws = (char*)d_ws;
    _Float16* Mh    = (_Float16*)ws;     ws += (size_t)N_NODES * DIM * sizeof(_Float16);
    float* es       = (float*)ws;        ws += (size_t)N_NODES * sizeof(float);
    int* cursor     = (int*)ws;          ws += (size_t)2048 * sizeof(int);
    unsigned int* pairs = (unsigned int*)ws; ws += (size_t)NBF * CAP * sizeof(unsigned int);

    hipMemsetAsync(cursor, 0, NBF * sizeof(int), stream);

    k_phase<<<PH_BLOCKS, 1024, 0, stream>>>(x, Wm, bm, Wr, br, row, col,
                                            cursor, pairs, Mh, es, out);
    k_bucket_gather<<<NBF, 512, 0, stream>>>(pairs, cursor, es,
                                             (const half4*)Mh, (float4*)out);
}

// Round 7
// 158.471 us; speedup vs baseline: 1.1785x; 1.1785x over previous
//
#include <hip/hip_runtime.h>
#include <math.h>

#define N_NODES 100000
#define DIM 64
#define N_EDGES 1600000

#define NBF 1563        // fine buckets: col >> 6 (ceil(100000/64) = 1563)
#define BK_NODES 64
#define CAP 1408        // per-bucket slab capacity (mean 1024, sigma ~32)

#define SC_CHUNK 8192
#define SC_BLOCKS ((N_EDGES + SC_CHUNK - 1) / SC_CHUNK)  // 196

#define GEMM_BLOCKS ((N_NODES / 16 + 15) / 16)  // 391 blocks x 16 waves
#define PH_BLOCKS (SC_BLOCKS + GEMM_BLOCKS)     // 587

typedef _Float16 half8 __attribute__((ext_vector_type(8)));
typedef _Float16 half4 __attribute__((ext_vector_type(4)));
typedef float f32x4 __attribute__((ext_vector_type(4)));

// ---------------------------------------------------------------------------
// Fused phase (block-specialized, 1024 threads) — byte-identical to round 1
// (best measured). Scan+stage scatter keeps pairs writes in long coalesced
// runs; GEMM branch runs concurrently on other CUs.
// ---------------------------------------------------------------------------
__global__ __launch_bounds__(1024) void k_phase(
        const float* __restrict__ x,
        const float* __restrict__ Wm, const float* __restrict__ bm,
        const float* __restrict__ Wr, const float* __restrict__ br,
        const int* __restrict__ row, const int* __restrict__ col,
        int* __restrict__ cursor, unsigned int* __restrict__ pairs,
        _Float16* __restrict__ Mh, float* __restrict__ es,
        float* __restrict__ out) {
    __shared__ int cnt[NBF];     // histogram, then rebase (base_g - base_l)
    __shared__ int base_l[NBF];
    __shared__ int wsum[16];
    __shared__ int segtot;
    __shared__ unsigned int stage[SC_CHUNK];
    __shared__ unsigned short stage_bk[SC_CHUNK];

    const int t = threadIdx.x;
    const int lane = t & 63;
    const int wid = t >> 6;

    if (blockIdx.x < SC_BLOCKS) {
        const int start = blockIdx.x * SC_CHUNK;
        const int mEnd = min(N_EDGES, start + SC_CHUNK);

        for (int i = t; i < NBF; i += 1024) cnt[i] = 0;
        __syncthreads();

        int rr[8], cc[8], lr[8];
#pragma unroll
        for (int k = 0; k < 8; ++k) {
            const int idx = start + k * 1024 + t;
            if (idx < mEnd) {
                cc[k] = col[idx];
                rr[k] = row[idx];
                lr[k] = atomicAdd(&cnt[cc[k] >> 6], 1);
            }
        }
        __syncthreads();

        // segmented two-level exclusive scan over cnt[0..NBF): two 1024-wide
        // passes with carry (NBF = 1563 > blockDim).
        int segbase = 0;
        for (int s = 0; s < NBF; s += 1024) {
            const int i = s + t;
            const int v = (i < NBF) ? cnt[i] : 0;
            int inc = v;
#pragma unroll
            for (int o = 1; o < 64; o <<= 1) {
                const int u = __shfl_up(inc, o, 64);
                if (lane >= o) inc += u;
            }
            if (lane == 63) wsum[wid] = inc;
            __syncthreads();
            if (wid == 0) {
                const int wv = (lane < 16) ? wsum[lane] : 0;
                int winc = wv;
#pragma unroll
                for (int o = 1; o < 16; o <<= 1) {
                    const int u = __shfl_up(winc, o, 64);
                    if (lane >= o) winc += u;
                }
                if (lane < 16) wsum[lane] = winc - wv;  // exclusive wave offsets
            }
            __syncthreads();
            const int excl = segbase + inc - v + wsum[wid];
            if (i < NBF) {
                base_l[i] = excl;
                // rebase: gslot = base_g + (i - base_l) = cnt[i] + i later
                if (v > 0) cnt[i] = atomicAdd(&cursor[i], v) - excl;
            }
            if (t == 1023) segtot = excl + v;  // inclusive total of this segment
            __syncthreads();
            segbase = segtot;
        }

#pragma unroll
        for (int k = 0; k < 8; ++k) {
            const int idx = start + k * 1024 + t;
            if (idx < mEnd) {
                const int bk = cc[k] >> 6;
                const int slot = base_l[bk] + lr[k];
                stage[slot] = ((unsigned int)rr[k] << 6) | (unsigned int)(cc[k] & 63);
                stage_bk[slot] = (unsigned short)bk;
            }
        }
        __syncthreads();

        const int m = mEnd - start;
        for (int i = t; i < m; i += 1024) {
            const int bk = stage_bk[i];
            const int gslot = cnt[bk] + i;  // (base_g - base_l) + i
            if (gslot < CAP) pairs[(size_t)bk * CAP + gslot] = stage[i];
        }
        return;
    }

    // ---- GEMM branch ----
    const int wave = (blockIdx.x - SC_BLOCKS) * 16 + wid;
    if (wave >= N_NODES / 16) return;
    const int quad = lane >> 4;
    const int l15 = lane & 15;
    const int row0 = wave * 16;

    half8 bfrag[8][2];
#pragma unroll
    for (int ct = 0; ct < 8; ++ct) {
        const float* W = (ct < 4) ? Wm : Wr;
        const int c = (ct & 3) * 16 + l15;
#pragma unroll
        for (int kc = 0; kc < 2; ++kc) {
            half8 f;
#pragma unroll
            for (int j = 0; j < 8; ++j)
                f[j] = (_Float16)W[(kc * 32 + quad * 8 + j) * DIM + c];
            bfrag[ct][kc] = f;
        }
    }

    half8 afrag[2];
#pragma unroll
    for (int kc = 0; kc < 2; ++kc) {
        const float* xp = x + (size_t)(row0 + l15) * DIM + kc * 32 + quad * 8;
        const float4 x0 = *(const float4*)xp;
        const float4 x1 = *(const float4*)(xp + 4);
        half8 f;
        f[0] = (_Float16)x0.x; f[1] = (_Float16)x0.y;
        f[2] = (_Float16)x0.z; f[3] = (_Float16)x0.w;
        f[4] = (_Float16)x1.x; f[5] = (_Float16)x1.y;
        f[6] = (_Float16)x1.z; f[7] = (_Float16)x1.w;
        afrag[kc] = f;
    }

    f32x4 acc[8];
#pragma unroll
    for (int ct = 0; ct < 8; ++ct) {
        f32x4 a = {0.f, 0.f, 0.f, 0.f};
        a = __builtin_amdgcn_mfma_f32_16x16x32_f16(afrag[0], bfrag[ct][0], a, 0, 0, 0);
        a = __builtin_amdgcn_mfma_f32_16x16x32_f16(afrag[1], bfrag[ct][1], a, 0, 0, 0);
        acc[ct] = a;
    }

    float rsum[4] = {0.f, 0.f, 0.f, 0.f};
#pragma unroll
    for (int ct = 0; ct < 8; ++ct) {
        const float bias = (ct < 4) ? bm[(ct & 3) * 16 + l15]
                                    : br[(ct & 3) * 16 + l15];
#pragma unroll
        for (int r = 0; r < 4; ++r) {
            const float v = acc[ct][r] + bias;
            const size_t idx = (size_t)(row0 + quad * 4 + r) * DIM + (ct & 3) * 16 + l15;
            if (ct < 4) {
                Mh[idx] = (_Float16)v;
                rsum[r] += v;
            } else {
                out[idx] = v;
            }
        }
    }
#pragma unroll
    for (int o = 1; o <= 8; o <<= 1) {
#pragma unroll
        for (int r = 0; r < 4; ++r) rsum[r] += __shfl_xor(rsum[r], o, 64);
    }
    if (l15 == 0) {
#pragma unroll
        for (int r = 0; r < 4; ++r)
            es[row0 + quad * 4 + r] = __expf(rsum[r] * (1.0f / DIM));
    }
}

// ---------------------------------------------------------------------------
// Bucket gather: one 512-thread block per fine bucket (64 dst nodes).
// Round-1 structure (proven); ONE change: after the counting sort, a batched
// high-MLP pass stages es[src] for the whole bucket into LDS, removing the
// random ~200-cycle es load from every edge's critical dependency chain.
// Compute loop: LDS sorted read + LDS es read + Mh row load + FMAs (4-deep).
// ---------------------------------------------------------------------------
__global__ __launch_bounds__(512) void k_bucket_gather(
        const unsigned int* __restrict__ pairs, const int* __restrict__ cursor,
        const float* __restrict__ es, const half4* __restrict__ Mh4,
        float4* __restrict__ out4) {
    __shared__ unsigned int sorted[CAP];      // 5.5 KB
    __shared__ float es_l[CAP];               // 5.5 KB staged weights
    __shared__ int cnt[BK_NODES];
    __shared__ int off[BK_NODES];
    const int b = blockIdx.x;
    const int t = threadIdx.x;
    const int lane = t & 63;
    const int wid = t >> 6;
    const int m = min(cursor[b], CAP);
    const size_t base = (size_t)b * CAP;

    if (t < BK_NODES) cnt[t] = 0;
    __syncthreads();

    unsigned int pk[3];
    int rk[3];
#pragma unroll
    for (int k = 0; k < 3; ++k) {
        const int i = k * 512 + t;
        if (i < m) {
            pk[k] = pairs[base + i];
            rk[k] = atomicAdd(&cnt[pk[k] & 63u], 1);
        }
    }
    __syncthreads();

    // exclusive scan over 64 counters: single wave shfl scan
    if (wid == 0) {
        const int v = cnt[lane];
        int inc = v;
#pragma unroll
        for (int o = 1; o < 64; o <<= 1) {
            const int u = __shfl_up(inc, o, 64);
            if (lane >= o) inc += u;
        }
        off[lane] = inc - v;
    }
    __syncthreads();

#pragma unroll
    for (int k = 0; k < 3; ++k) {
        const int i = k * 512 + t;
        if (i < m) sorted[off[pk[k] & 63u] + rk[k]] = pk[k];
    }
    __syncthreads();

    // batched es staging: 512 threads x 3-deep random loads, full MLP,
    // off the per-edge critical path.
    for (int i = t; i < m; i += 512)
        es_l[i] = es[(int)(sorted[i] >> 6)];
    __syncthreads();

    const int g = t >> 4;   // 32 groups of 16 lanes
    const int gl = t & 15;
    for (int c = g; c < BK_NODES; c += 32) {
        const int node = b * BK_NODES + c;
        if (node >= N_NODES) break;
        const int s0i = off[c];
        const int len = cnt[c];
        if (len == 0) continue;

        float a0x = 0.f, a0y = 0.f, a0z = 0.f, a0w = 0.f, l0 = 0.f;
        float a1x = 0.f, a1y = 0.f, a1z = 0.f, a1w = 0.f, l1 = 0.f;
        float a2x = 0.f, a2y = 0.f, a2z = 0.f, a2w = 0.f, l2 = 0.f;
        float a3x = 0.f, a3y = 0.f, a3z = 0.f, a3w = 0.f, l3 = 0.f;
        int j = 0;
        for (; j + 3 < len; j += 4) {
            const int s0 = (int)(sorted[s0i + j] >> 6);
            const int s1 = (int)(sorted[s0i + j + 1] >> 6);
            const int s2 = (int)(sorted[s0i + j + 2] >> 6);
            const int s3 = (int)(sorted[s0i + j + 3] >> 6);
            const float w0 = es_l[s0i + j];
            const float w1 = es_l[s0i + j + 1];
            const float w2 = es_l[s0i + j + 2];
            const float w3 = es_l[s0i + j + 3];
            const half4 m0 = Mh4[(size_t)s0 * 16 + gl];
            const half4 m1 = Mh4[(size_t)s1 * 16 + gl];
            const half4 m2 = Mh4[(size_t)s2 * 16 + gl];
            const half4 m3 = Mh4[(size_t)s3 * 16 + gl];
            l0 += w0; l1 += w1; l2 += w2; l3 += w3;
            a0x = fmaf(w0, (float)m0[0], a0x); a0y = fmaf(w0, (float)m0[1], a0y);
            a0z = fmaf(w0, (float)m0[2], a0z); a0w = fmaf(w0, (float)m0[3], a0w);
            a1x = fmaf(w1, (float)m1[0], a1x); a1y = fmaf(w1, (float)m1[1], a1y);
            a1z = fmaf(w1, (float)m1[2], a1z); a1w = fmaf(w1, (float)m1[3], a1w);
            a2x = fmaf(w2, (float)m2[0], a2x); a2y = fmaf(w2, (float)m2[1], a2y);
            a2z = fmaf(w2, (float)m2[2], a2z); a2w = fmaf(w2, (float)m2[3], a2w);
            a3x = fmaf(w3, (float)m3[0], a3x); a3y = fmaf(w3, (float)m3[1], a3y);
            a3z = fmaf(w3, (float)m3[2], a3z); a3w = fmaf(w3, (float)m3[3], a3w);
        }
        for (; j < len; ++j) {
            const int s0 = (int)(sorted[s0i + j] >> 6);
            const float w0 = es_l[s0i + j];
            const half4 m0 = Mh4[(size_t)s0 * 16 + gl];
            l0 += w0;
            a0x = fmaf(w0, (float)m0[0], a0x); a0y = fmaf(w0, (float)m0[1], a0y);
            a0z = fmaf(w0, (float)m0[2], a0z); a0w = fmaf(w0, (float)m0[3], a0w);
        }
        const float inv = 1.0f / (l0 + l1 + l2 + l3);
        float4 r = out4[(size_t)node * 16 + gl];
        r.x = fmaf(a0x + a1x + a2x + a3x, inv, r.x);
        r.y = fmaf(a0y + a1y + a2y + a3y, inv, r.y);
        r.z = fmaf(a0z + a1z + a2z + a3z, inv, r.z);
        r.w = fmaf(a0w + a1w + a2w + a3w, inv, r.w);
        out4[(size_t)node * 16 + gl] = r;
    }
}

// ---------------------------------------------------------------------------
extern "C" void kernel_launch(void* const* d_in, const int* in_sizes, int n_in,
                              void* d_out, int out_size, void* d_ws, size_t ws_size,
                              hipStream_t stream) {
    const float* x  = (const float*)d_in[0];
    const int*   ei = (const int*)d_in[1];
    const float* Wm = (const float*)d_in[2];
    const float* bm = (const float*)d_in[3];
    const float* Wr = (const float*)d_in[4];
    const float* br = (const float*)d_in[5];
    float* out = (float*)d_out;
    const int* row = ei;            // edge_index[0]
    const int* col = ei + N_EDGES;  // edge_index[1]

    char* ws = (char*)d_ws;
    _Float16* Mh    = (_Float16*)ws;     ws += (size_t)N_NODES * DIM * sizeof(_Float16);
    float* es       = (float*)ws;        ws += (size_t)N_NODES * sizeof(float);
    int* cursor     = (int*)ws;          ws += (size_t)2048 * sizeof(int);
    unsigned int* pairs = (unsigned int*)ws; ws += (size_t)NBF * CAP * sizeof(unsigned int);

    hipMemsetAsync(cursor, 0, NBF * sizeof(int), stream);

    k_phase<<<PH_BLOCKS, 1024, 0, stream>>>(x, Wm, bm, Wr, br, row, col,
                                            cursor, pairs, Mh, es, out);
    k_bucket_gather<<<NBF, 512, 0, stream>>>(pairs, cursor, es,
                                             (const half4*)Mh, (float4*)out);
}

// Round 8
// 152.309 us; speedup vs baseline: 1.2262x; 1.0405x over previous
//
#include <hip/hip_runtime.h>
#include <math.h>

#define N_NODES 100000
#define DIM 64
#define N_EDGES 1600000

#define NBF 1563        // fine buckets: col >> 6 (ceil(100000/64) = 1563)
#define BK_NODES 64
#define CAP 1408        // per-bucket slab capacity (mean 1024, sigma ~32)

#define CFLAG 2047      // flag slot in cursor[] (line not shared with live counters)
#define CMAGIC 0x1357ACE9

#define SC_CHUNK 8192
#define SC_BLOCKS ((N_EDGES + SC_CHUNK - 1) / SC_CHUNK)  // 196

#define GEMM_BLOCKS ((N_NODES / 16 + 15) / 16)  // 391 blocks x 16 waves
#define PH_BLOCKS (SC_BLOCKS + GEMM_BLOCKS)     // 587

typedef _Float16 half8 __attribute__((ext_vector_type(8)));
typedef _Float16 half4 __attribute__((ext_vector_type(4)));
typedef float f32x4 __attribute__((ext_vector_type(4)));

// ---------------------------------------------------------------------------
// Fused phase (block-specialized, 1024 threads) — round-1 anchor, plus
// in-kernel cursor zeroing (removes the hipMemsetAsync dispatch, ~10 us gap):
// scatter block 0 zeroes cursor[0..NBF) with device-scope atomics, fences,
// then publishes CMAGIC at cursor[CFLAG]; scatter blocks spin (1 lane) on the
// flag only right before their global rebase atomics, overlapped with the
// LDS histogram + scan. All scatter blocks are co-resident -> deadlock-free.
// ---------------------------------------------------------------------------
__global__ __launch_bounds__(1024) void k_phase(
        const float* __restrict__ x,
        const float* __restrict__ Wm, const float* __restrict__ bm,
        const float* __restrict__ Wr, const float* __restrict__ br,
        const int* __restrict__ row, const int* __restrict__ col,
        int* __restrict__ cursor, unsigned int* __restrict__ pairs,
        _Float16* __restrict__ Mh, float* __restrict__ es,
        float* __restrict__ out) {
    __shared__ int cnt[NBF];     // histogram, then rebase (base_g - base_l)
    __shared__ int base_l[NBF];
    __shared__ int wsum[16];
    __shared__ int segtot;
    __shared__ unsigned int stage[SC_CHUNK];
    __shared__ unsigned short stage_bk[SC_CHUNK];

    const int t = threadIdx.x;
    const int lane = t & 63;
    const int wid = t >> 6;

    if (blockIdx.x < SC_BLOCKS) {
        if (blockIdx.x == 0) {
            // zero the bucket cursors (device-scope) and publish the flag
            for (int i = t; i < NBF; i += 1024) atomicExch(&cursor[i], 0);
            __syncthreads();
            if (t == 0) {
                __threadfence();
                atomicExch(&cursor[CFLAG], CMAGIC);
            }
        }

        const int start = blockIdx.x * SC_CHUNK;
        const int mEnd = min(N_EDGES, start + SC_CHUNK);

        for (int i = t; i < NBF; i += 1024) cnt[i] = 0;
        __syncthreads();

        int rr[8], cc[8], lr[8];
#pragma unroll
        for (int k = 0; k < 8; ++k) {
            const int idx = start + k * 1024 + t;
            if (idx < mEnd) {
                cc[k] = col[idx];
                rr[k] = row[idx];
                lr[k] = atomicAdd(&cnt[cc[k] >> 6], 1);
            }
        }
        __syncthreads();

        // wait (1 lane) until cursors are zeroed; overlapped with the above
        if (t == 0) {
            while (atomicAdd(&cursor[CFLAG], 0) != CMAGIC) {}
        }
        __syncthreads();

        // segmented two-level exclusive scan over cnt[0..NBF): two 1024-wide
        // passes with carry (NBF = 1563 > blockDim).
        int segbase = 0;
        for (int s = 0; s < NBF; s += 1024) {
            const int i = s + t;
            const int v = (i < NBF) ? cnt[i] : 0;
            int inc = v;
#pragma unroll
            for (int o = 1; o < 64; o <<= 1) {
                const int u = __shfl_up(inc, o, 64);
                if (lane >= o) inc += u;
            }
            if (lane == 63) wsum[wid] = inc;
            __syncthreads();
            if (wid == 0) {
                const int wv = (lane < 16) ? wsum[lane] : 0;
                int winc = wv;
#pragma unroll
                for (int o = 1; o < 16; o <<= 1) {
                    const int u = __shfl_up(winc, o, 64);
                    if (lane >= o) winc += u;
                }
                if (lane < 16) wsum[lane] = winc - wv;  // exclusive wave offsets
            }
            __syncthreads();
            const int excl = segbase + inc - v + wsum[wid];
            if (i < NBF) {
                base_l[i] = excl;
                // rebase: gslot = base_g + (i - base_l) = cnt[i] + i later
                if (v > 0) cnt[i] = atomicAdd(&cursor[i], v) - excl;
            }
            if (t == 1023) segtot = excl + v;  // inclusive total of this segment
            __syncthreads();
            segbase = segtot;
        }

#pragma unroll
        for (int k = 0; k < 8; ++k) {
            const int idx = start + k * 1024 + t;
            if (idx < mEnd) {
                const int bk = cc[k] >> 6;
                const int slot = base_l[bk] + lr[k];
                stage[slot] = ((unsigned int)rr[k] << 6) | (unsigned int)(cc[k] & 63);
                stage_bk[slot] = (unsigned short)bk;
            }
        }
        __syncthreads();

        const int m = mEnd - start;
        for (int i = t; i < m; i += 1024) {
            const int bk = stage_bk[i];
            const int gslot = cnt[bk] + i;  // (base_g - base_l) + i
            if (gslot < CAP) pairs[(size_t)bk * CAP + gslot] = stage[i];
        }
        return;
    }

    // ---- GEMM branch ----
    const int wave = (blockIdx.x - SC_BLOCKS) * 16 + wid;
    if (wave >= N_NODES / 16) return;
    const int quad = lane >> 4;
    const int l15 = lane & 15;
    const int row0 = wave * 16;

    half8 bfrag[8][2];
#pragma unroll
    for (int ct = 0; ct < 8; ++ct) {
        const float* W = (ct < 4) ? Wm : Wr;
        const int c = (ct & 3) * 16 + l15;
#pragma unroll
        for (int kc = 0; kc < 2; ++kc) {
            half8 f;
#pragma unroll
            for (int j = 0; j < 8; ++j)
                f[j] = (_Float16)W[(kc * 32 + quad * 8 + j) * DIM + c];
            bfrag[ct][kc] = f;
        }
    }

    half8 afrag[2];
#pragma unroll
    for (int kc = 0; kc < 2; ++kc) {
        const float* xp = x + (size_t)(row0 + l15) * DIM + kc * 32 + quad * 8;
        const float4 x0 = *(const float4*)xp;
        const float4 x1 = *(const float4*)(xp + 4);
        half8 f;
        f[0] = (_Float16)x0.x; f[1] = (_Float16)x0.y;
        f[2] = (_Float16)x0.z; f[3] = (_Float16)x0.w;
        f[4] = (_Float16)x1.x; f[5] = (_Float16)x1.y;
        f[6] = (_Float16)x1.z; f[7] = (_Float16)x1.w;
        afrag[kc] = f;
    }

    f32x4 acc[8];
#pragma unroll
    for (int ct = 0; ct < 8; ++ct) {
        f32x4 a = {0.f, 0.f, 0.f, 0.f};
        a = __builtin_amdgcn_mfma_f32_16x16x32_f16(afrag[0], bfrag[ct][0], a, 0, 0, 0);
        a = __builtin_amdgcn_mfma_f32_16x16x32_f16(afrag[1], bfrag[ct][1], a, 0, 0, 0);
        acc[ct] = a;
    }

    float rsum[4] = {0.f, 0.f, 0.f, 0.f};
#pragma unroll
    for (int ct = 0; ct < 8; ++ct) {
        const float bias = (ct < 4) ? bm[(ct & 3) * 16 + l15]
                                    : br[(ct & 3) * 16 + l15];
#pragma unroll
        for (int r = 0; r < 4; ++r) {
            const float v = acc[ct][r] + bias;
            const size_t idx = (size_t)(row0 + quad * 4 + r) * DIM + (ct & 3) * 16 + l15;
            if (ct < 4) {
                Mh[idx] = (_Float16)v;
                rsum[r] += v;
            } else {
                out[idx] = v;
            }
        }
    }
#pragma unroll
    for (int o = 1; o <= 8; o <<= 1) {
#pragma unroll
        for (int r = 0; r < 4; ++r) rsum[r] += __shfl_xor(rsum[r], o, 64);
    }
    if (l15 == 0) {
#pragma unroll
        for (int r = 0; r < 4; ++r)
            es[row0 + quad * 4 + r] = __expf(rsum[r] * (1.0f / DIM));
    }
}

// ---------------------------------------------------------------------------
// Bucket gather: one 512-thread block per fine bucket (64 dst nodes).
// Byte-identical to the round-1 version (best measured; es-LDS staging
// variant from round 7 regressed +3.5 us and is reverted).
// ---------------------------------------------------------------------------
__global__ __launch_bounds__(512) void k_bucket_gather(
        const unsigned int* __restrict__ pairs, const int* __restrict__ cursor,
        const float* __restrict__ es, const half4* __restrict__ Mh4,
        float4* __restrict__ out4) {
    __shared__ unsigned int sorted[CAP];      // 5.5 KB
    __shared__ int cnt[BK_NODES];
    __shared__ int off[BK_NODES];
    const int b = blockIdx.x;
    const int t = threadIdx.x;
    const int lane = t & 63;
    const int wid = t >> 6;
    const int m = min(cursor[b], CAP);
    const size_t base = (size_t)b * CAP;

    if (t < BK_NODES) cnt[t] = 0;
    __syncthreads();

    unsigned int pk[3];
    int rk[3];
#pragma unroll
    for (int k = 0; k < 3; ++k) {
        const int i = k * 512 + t;
        if (i < m) {
            pk[k] = pairs[base + i];
            rk[k] = atomicAdd(&cnt[pk[k] & 63u], 1);
        }
    }
    __syncthreads();

    // exclusive scan over 64 counters: single wave shfl scan
    if (wid == 0) {
        const int v = cnt[lane];
        int inc = v;
#pragma unroll
        for (int o = 1; o < 64; o <<= 1) {
            const int u = __shfl_up(inc, o, 64);
            if (lane >= o) inc += u;
        }
        off[lane] = inc - v;
    }
    __syncthreads();

#pragma unroll
    for (int k = 0; k < 3; ++k) {
        const int i = k * 512 + t;
        if (i < m) sorted[off[pk[k] & 63u] + rk[k]] = pk[k];
    }
    __syncthreads();

    const int g = t >> 4;   // 32 groups of 16 lanes
    const int gl = t & 15;
    for (int c = g; c < BK_NODES; c += 32) {
        const int node = b * BK_NODES + c;
        if (node >= N_NODES) break;
        const int s0i = off[c];
        const int len = cnt[c];
        if (len == 0) continue;

        float a0x = 0.f, a0y = 0.f, a0z = 0.f, a0w = 0.f, l0 = 0.f;
        float a1x = 0.f, a1y = 0.f, a1z = 0.f, a1w = 0.f, l1 = 0.f;
        float a2x = 0.f, a2y = 0.f, a2z = 0.f, a2w = 0.f, l2 = 0.f;
        float a3x = 0.f, a3y = 0.f, a3z = 0.f, a3w = 0.f, l3 = 0.f;
        int j = 0;
        for (; j + 3 < len; j += 4) {
            const int s0 = (int)(sorted[s0i + j] >> 6);
            const int s1 = (int)(sorted[s0i + j + 1] >> 6);
            const int s2 = (int)(sorted[s0i + j + 2] >> 6);
            const int s3 = (int)(sorted[s0i + j + 3] >> 6);
            const float w0 = es[s0];
            const float w1 = es[s1];
            const float w2 = es[s2];
            const float w3 = es[s3];
            const half4 m0 = Mh4[(size_t)s0 * 16 + gl];
            const half4 m1 = Mh4[(size_t)s1 * 16 + gl];
            const half4 m2 = Mh4[(size_t)s2 * 16 + gl];
            const half4 m3 = Mh4[(size_t)s3 * 16 + gl];
            l0 += w0; l1 += w1; l2 += w2; l3 += w3;
            a0x = fmaf(w0, (float)m0[0], a0x); a0y = fmaf(w0, (float)m0[1], a0y);
            a0z = fmaf(w0, (float)m0[2], a0z); a0w = fmaf(w0, (float)m0[3], a0w);
            a1x = fmaf(w1, (float)m1[0], a1x); a1y = fmaf(w1, (float)m1[1], a1y);
            a1z = fmaf(w1, (float)m1[2], a1z); a1w = fmaf(w1, (float)m1[3], a1w);
            a2x = fmaf(w2, (float)m2[0], a2x); a2y = fmaf(w2, (float)m2[1], a2y);
            a2z = fmaf(w2, (float)m2[2], a2z); a2w = fmaf(w2, (float)m2[3], a2w);
            a3x = fmaf(w3, (float)m3[0], a3x); a3y = fmaf(w3, (float)m3[1], a3y);
            a3z = fmaf(w3, (float)m3[2], a3z); a3w = fmaf(w3, (float)m3[3], a3w);
        }
        if (j < len) {
            const int s0 = (int)(sorted[s0i + j] >> 6);
            const float w0 = es[s0];
            const half4 m0 = Mh4[(size_t)s0 * 16 + gl];
            l0 += w0;
            a0x = fmaf(w0, (float)m0[0], a0x); a0y = fmaf(w0, (float)m0[1], a0y);
            a0z = fmaf(w0, (float)m0[2], a0z); a0w = fmaf(w0, (float)m0[3], a0w);
            ++j;
            if (j < len) {
                const int s1 = (int)(sorted[s0i + j] >> 6);
                const float w1 = es[s1];
                const half4 m1 = Mh4[(size_t)s1 * 16 + gl];
                l1 += w1;
                a1x = fmaf(w1, (float)m1[0], a1x); a1y = fmaf(w1, (float)m1[1], a1y);
                a1z = fmaf(w1, (float)m1[2], a1z); a1w = fmaf(w1, (float)m1[3], a1w);
                ++j;
                if (j < len) {
                    const int s2 = (int)(sorted[s0i + j] >> 6);
                    const float w2 = es[s2];
                    const half4 m2 = Mh4[(size_t)s2 * 16 + gl];
                    l2 += w2;
                    a2x = fmaf(w2, (float)m2[0], a2x); a2y = fmaf(w2, (float)m2[1], a2y);
                    a2z = fmaf(w2, (float)m2[2], a2z); a2w = fmaf(w2, (float)m2[3], a2w);
                }
            }
        }
        const float inv = 1.0f / (l0 + l1 + l2 + l3);
        float4 r = out4[(size_t)node * 16 + gl];
        r.x = fmaf(a0x + a1x + a2x + a3x, inv, r.x);
        r.y = fmaf(a0y + a1y + a2y + a3y, inv, r.y);
        r.z = fmaf(a0z + a1z + a2z + a3z, inv, r.z);
        r.w = fmaf(a0w + a1w + a2w + a3w, inv, r.w);
        out4[(size_t)node * 16 + gl] = r;
    }
}

// ---------------------------------------------------------------------------
extern "C" void kernel_launch(void* const* d_in, const int* in_sizes, int n_in,
                              void* d_out, int out_size, void* d_ws, size_t ws_size,
                              hipStream_t stream) {
    const float* x  = (const float*)d_in[0];
    const int*   ei = (const int*)d_in[1];
    const float* Wm = (const float*)d_in[2];
    const float* bm = (const float*)d_in[3];
    const float* Wr = (const float*)d_in[4];
    const float* br = (const float*)d_in[5];
    float* out = (float*)d_out;
    const int* row = ei;            // edge_index[0]
    const int* col = ei + N_EDGES;  // edge_index[1]

    char* ws = (char*)d_ws;
    _Float16* Mh    = (_Float16*)ws;     ws += (size_t)N_NODES * DIM * sizeof(_Float16);
    float* es       = (float*)ws;        ws += (size_t)N_NODES * sizeof(float);
    int* cursor     = (int*)ws;          ws += (size_t)2048 * sizeof(int);
    unsigned int* pairs = (unsigned int*)ws; ws += (size_t)NBF * CAP * sizeof(unsigned int);

    k_phase<<<PH_BLOCKS, 1024, 0, stream>>>(x, Wm, bm, Wr, br, row, col,
                                            cursor, pairs, Mh, es, out);
    k_bucket_gather<<<NBF, 512, 0, stream>>>(pairs, cursor, es,
                                             (const half4*)Mh, (float4*)out);
}